// Round 6
// baseline (254.050 us; speedup 1.0000x reference)
//
#include <hip/hip_runtime.h>

#define NNODES 50000
#define MPAD   50048    // padded to multiple of 64 for MFMA tiles; rows 50000.. are zero pads
#define NEDGES 800000
#define KDIM   256      // in/hidden feature dim (GEMM K)
#define FH     256      // hidden feats
#define FOUT   128      // out feats
#define FCH    32       // feature chunk (bf16): 64B contiguous per node in blocked layout

// ---- counting-sort geometry ----
#define SHIFT  8
#define NBUCK  196              // ceil(50000/256); max dst>>8 = 195
#define NB1    200              // level-1 blocks
#define EPB    4000             // edges per level-1 block (NB1*EPB == NEDGES)

typedef __bf16 bf16x8 __attribute__((ext_vector_type(8)));
typedef float floatx4 __attribute__((ext_vector_type(4)));

// ---------------- bf16 helpers (RNE) ----------------
__device__ __forceinline__ float bf2f(unsigned short u) {
    union { unsigned int i; float f; } v;
    v.i = ((unsigned int)u) << 16;
    return v.f;
}
__device__ __forceinline__ unsigned short f2bf(float f) {
    union { float f; unsigned int i; } v;
    v.f = f;
    unsigned int r = v.i + 0x7FFFu + ((v.i >> 16) & 1u);
    return (unsigned short)(r >> 16);
}

// ============ P1: per-block counting sort, block-major output (no global scan needed)
__global__ __launch_bounds__(256) void l1_sort_cast(const int* __restrict__ src,
                                                    const int* __restrict__ dst,
                                                    unsigned int* __restrict__ tmp1,
                                                    unsigned char* __restrict__ tmp2,
                                                    int* __restrict__ exD_arr,
                                                    int* __restrict__ exS_arr,
                                                    const float* __restrict__ W1,
                                                    unsigned short* __restrict__ Wt1,
                                                    const float* __restrict__ W2,
                                                    unsigned short* __restrict__ Wt2) {
    __shared__ int histD[256], histS[256], exD[256], exS[256];
    __shared__ unsigned int bufD[EPB];
    __shared__ unsigned short bufS[EPB];
    __shared__ float tile[32][33];
    const int tid = threadIdx.x;

    if (blockIdx.x >= NB1) {
        int b = blockIdx.x - NB1;
        const float* W; unsigned short* Wt; int N;
        if (b < 64) { W = W1; Wt = Wt1; N = FH; }
        else        { b -= 64; W = W2; Wt = Wt2; N = FOUT; }
        int kt = (b & 7) * 32;
        int nt = (b >> 3) * 32;
        int tx = tid & 31;
        int ty = tid >> 5;
        for (int r = ty; r < 32; r += 8)
            tile[r][tx] = W[(size_t)(kt + r) * N + nt + tx];
        __syncthreads();
        for (int r = ty; r < 32; r += 8)
            Wt[(size_t)(nt + r) * KDIM + kt + tx] = f2bf(tile[tx][r]);
        return;
    }

    const int b = blockIdx.x;
    const int base = b * EPB;
    histD[tid] = 0; histS[tid] = 0;
    __syncthreads();
    for (int g = tid; g < EPB / 4; g += 256) {
        uint4 s4 = *(const uint4*)(src + base + g * 4);
        uint4 d4 = *(const uint4*)(dst + base + g * 4);
        atomicAdd(&histD[d4.x >> SHIFT], 1);
        atomicAdd(&histD[d4.y >> SHIFT], 1);
        atomicAdd(&histD[d4.z >> SHIFT], 1);
        atomicAdd(&histD[d4.w >> SHIFT], 1);
        atomicAdd(&histS[s4.x >> SHIFT], 1);
        atomicAdd(&histS[s4.y >> SHIFT], 1);
        atomicAdd(&histS[s4.z >> SHIFT], 1);
        atomicAdd(&histS[s4.w >> SHIFT], 1);
    }
    __syncthreads();
    int vD = histD[tid], vS = histS[tid];
    exD[tid] = vD; exS[tid] = vS;
    __syncthreads();
    for (int off = 1; off < 256; off <<= 1) {
        int tD = (tid >= off) ? exD[tid - off] : 0;
        int tS = (tid >= off) ? exS[tid - off] : 0;
        __syncthreads();
        exD[tid] += tD; exS[tid] += tS;
        __syncthreads();
    }
    int eD = exD[tid] - vD, eS = exS[tid] - vS;
    exD_arr[tid * NB1 + b] = eD;
    exS_arr[tid * NB1 + b] = eS;
    __syncthreads();
    histD[tid] = eD; histS[tid] = eS;
    __syncthreads();
    for (int g = tid; g < EPB / 4; g += 256) {
        uint4 s4 = *(const uint4*)(src + base + g * 4);
        uint4 d4 = *(const uint4*)(dst + base + g * 4);
        unsigned int ss[4] = {s4.x, s4.y, s4.z, s4.w};
        unsigned int dd[4] = {d4.x, d4.y, d4.z, d4.w};
#pragma unroll
        for (int j = 0; j < 4; ++j) {
            int p = atomicAdd(&histD[dd[j] >> SHIFT], 1);
            bufD[p] = (ss[j] << 16) | dd[j];
            int q = atomicAdd(&histS[ss[j] >> SHIFT], 1);
            bufS[q] = (unsigned short)ss[j];
        }
    }
    __syncthreads();
    for (int e = tid; e < EPB; e += 256) tmp1[base + e] = bufD[e];
    for (int e = tid; e < EPB; e += 256) tmp2[base + e] = (unsigned char)(bufS[e] & 255u);
}

// ============ P2: per-bucket finalize (dst: row_ptr/norm_dst/csr; src: norm_src) ==========
__global__ __launch_bounds__(256) void l2_both(const unsigned int* __restrict__ tmp1,
                                               const unsigned char* __restrict__ tmp2,
                                               const int* __restrict__ exD_arr,
                                               const int* __restrict__ exS_arr,
                                               int* __restrict__ row_ptr,
                                               float* __restrict__ norm_dst,
                                               float* __restrict__ norm_src,
                                               int* __restrict__ csr_src) {
    __shared__ int cnt[256], ofs[256], cur[256], red[256];
    __shared__ int segoff[NB1], seglen[NB1];
    const int tid = threadIdx.x;

    if (blockIdx.x >= NBUCK) {
        const int k = blockIdx.x - NBUCK;
        if (tid < NB1) {
            int e0 = exS_arr[k * NB1 + tid];
            segoff[tid] = tid * EPB + e0;
            seglen[tid] = exS_arr[(k + 1) * NB1 + tid] - e0;
        }
        cnt[tid] = 0;
        __syncthreads();
        if (tid < NB1) {
            int so = segoff[tid], sl = seglen[tid];
            for (int i = 0; i < sl; ++i)
                atomicAdd(&cnt[tmp2[so + i]], 1);
        }
        __syncthreads();
        int node = k * 256 + tid;
        if (node < NNODES) {
            int d = cnt[tid] < 1 ? 1 : cnt[tid];
            norm_src[node] = 1.0f / sqrtf((float)d);
        }
        return;
    }

    const int k = blockIdx.x;
    int e0v = 0;
    if (tid < NB1) {
        e0v = exD_arr[k * NB1 + tid];
        segoff[tid] = tid * EPB + e0v;
        seglen[tid] = exD_arr[(k + 1) * NB1 + tid] - e0v;
    }
    red[tid] = (tid < NB1) ? e0v : 0;
    cnt[tid] = 0;
    __syncthreads();
    for (int off = 128; off > 0; off >>= 1) {
        if (tid < off) red[tid] += red[tid + off];
        __syncthreads();
    }
    const int base = red[0];
    if (tid < NB1) {
        int so = segoff[tid], sl = seglen[tid];
        for (int i = 0; i < sl; ++i)
            atomicAdd(&cnt[tmp1[so + i] & 255u], 1);
    }
    __syncthreads();
    int v = cnt[tid];
    ofs[tid] = v;
    __syncthreads();
    for (int off = 1; off < 256; off <<= 1) {
        int t = (tid >= off) ? ofs[tid - off] : 0;
        __syncthreads();
        ofs[tid] += t;
        __syncthreads();
    }
    int excl = ofs[tid] - v;
    int node = k * 256 + tid;
    if (node < NNODES) {
        row_ptr[node] = base + excl;
        int d = v < 1 ? 1 : v;
        norm_dst[node] = 1.0f / sqrtf((float)d);
    }
    cur[tid] = base + excl;
    if (k == 0 && tid == 0) row_ptr[NNODES] = NEDGES;
    __syncthreads();
    if (tid < NB1) {
        int so = segoff[tid], sl = seglen[tid];
        for (int i = 0; i < sl; ++i) {
            unsigned int p = tmp1[so + i];
            int pos = atomicAdd(&cur[p & 255u], 1);
            csr_src[pos] = (int)(p >> 16);
        }
    }
}

// ================= B-resident GEMM; C written CHUNK-BLOCKED [(n/32)][MPAD][32] =============
struct arawF { float4 v[8]; float sc; };
struct arawU { uint4 v[4]; };
template <typename TA> struct rawsel;
template <> struct rawsel<float> { using type = arawF; };
template <> struct rawsel<unsigned short> { using type = arawU; };

__device__ __forceinline__ void loadA_raw(const float* A, const float* norm,
                                          int mt, int arow, int akseg, arawF& r) {
    int row = mt * 64 + arow;
    if (row < NNODES) {
        const float* p = A + (size_t)row * KDIM + akseg;
#pragma unroll
        for (int j = 0; j < 8; ++j) r.v[j] = *(const float4*)(p + j * 4);
        r.sc = norm[row];
    } else {
        float4 z = {0.f, 0.f, 0.f, 0.f};
#pragma unroll
        for (int j = 0; j < 8; ++j) r.v[j] = z;
        r.sc = 0.f;
    }
}
// h1 is chunk-blocked: feats akseg..akseg+31 of row = contiguous 64B at ((akseg/32)*MPAD+row)*32
__device__ __forceinline__ void loadA_raw(const unsigned short* A, const float*,
                                          int mt, int arow, int akseg, arawU& r) {
    const unsigned short* p = A + ((size_t)(akseg >> 5) * MPAD + mt * 64 + arow) * FCH;
#pragma unroll
    for (int j = 0; j < 4; ++j) r.v[j] = *(const uint4*)(p + j * 8);
}
__device__ __forceinline__ void writeA_lds(char* Asb, int arow, int akseg, const arawF& r) {
    const int s = (arow & 7) << 4;
    const int base = arow * 512;
#pragma unroll
    for (int j = 0; j < 4; ++j) {
        union { uint4 u; unsigned short h[8]; } o;
        float4 a = r.v[2 * j], b = r.v[2 * j + 1];
        o.h[0] = f2bf(a.x * r.sc); o.h[1] = f2bf(a.y * r.sc);
        o.h[2] = f2bf(a.z * r.sc); o.h[3] = f2bf(a.w * r.sc);
        o.h[4] = f2bf(b.x * r.sc); o.h[5] = f2bf(b.y * r.sc);
        o.h[6] = f2bf(b.z * r.sc); o.h[7] = f2bf(b.w * r.sc);
        *(uint4*)(Asb + base + (((akseg + j * 8) * 2) ^ s)) = o.u;
    }
}
__device__ __forceinline__ void writeA_lds(char* Asb, int arow, int akseg, const arawU& r) {
    const int s = (arow & 7) << 4;
    const int base = arow * 512;
#pragma unroll
    for (int j = 0; j < 4; ++j)
        *(uint4*)(Asb + base + (((akseg + j * 8) * 2) ^ s)) = r.v[j];
}

template <typename TA, bool SCALE, int NPANEL>
__global__ __launch_bounds__(512) void gemm_bres(const TA* __restrict__ A,
                                                 const unsigned short* __restrict__ Bt,
                                                 const float* __restrict__ norm,
                                                 unsigned short* __restrict__ C) {
    constexpr int NTILES = MPAD / 64;
    __shared__ __align__(16) unsigned short Bs[128 * 256];   // 64KB, [col][k] swizzled
    __shared__ __align__(16) unsigned short As[64 * 256];    // 32KB, [row][k] swizzled
    char* Bsb = (char*)Bs;
    char* Asb = (char*)As;

    const int tid = threadIdx.x;
    const int lane = tid & 63;
    const int wave = tid >> 6;

    int col0, mt0, mstep;
    if (NPANEL == 2) {
        col0 = ((blockIdx.x >> 3) & 1) * 128;
        mt0 = ((blockIdx.x >> 4) << 3) + (blockIdx.x & 7);
        mstep = gridDim.x >> 1;
    } else {
        col0 = 0;
        mt0 = blockIdx.x;
        mstep = gridDim.x;
    }

    {
        int col = tid >> 2;
        int kq = (tid & 3) * 64;
        const unsigned short* bg = Bt + (size_t)(col0 + col) * KDIM + kq;
        const int s = (col & 7) << 4;
        const int base = col * 512;
#pragma unroll
        for (int j = 0; j < 8; ++j) {
            uint4 v = *(const uint4*)(bg + j * 8);
            *(uint4*)(Bsb + base + (((kq + j * 8) * 2) ^ s)) = v;
        }
    }

    const int arow = tid >> 3;
    const int akseg = (tid & 7) * 32;

    typename rawsel<TA>::type buf;
    loadA_raw(A, norm, mt0, arow, akseg, buf);
    writeA_lds(Asb, arow, akseg, buf);
    __syncthreads();
    int mt = mt0, mtn = mt0 + mstep;
    if (mtn < NTILES) loadA_raw(A, norm, mtn, arow, akseg, buf);

    const int wn = wave & 3, wm = wave >> 2;
    const int ar = lane & 15;
    const int fkb = (lane >> 4) << 4;
    const int rA0 = wm * 32 + ar,  rA1 = rA0 + 16;
    const int cB0 = wn * 32 + ar,  cB1 = cB0 + 16;
    const int aO0 = rA0 * 512, aS0 = (rA0 & 7) << 4;
    const int aO1 = rA1 * 512, aS1 = (rA1 & 7) << 4;
    const int bO0 = cB0 * 512, bS0 = (cB0 & 7) << 4;
    const int bO1 = cB1 * 512, bS1 = (cB1 & 7) << 4;
    const int rb = (lane >> 4) << 2, cc = lane & 15;

    // chunk is wave-uniform: cols col0+wn*32 .. +31 == chunk (col0>>5)+wn
    unsigned short* Cb = C + ((size_t)((col0 >> 5) + wn) * MPAD) * FCH;

    for (;;) {
        floatx4 a00 = {}, a01 = {}, a10 = {}, a11 = {};
#pragma unroll
        for (int kk = 0; kk < 8; ++kk) {
            const int kb = kk * 64 + fkb;
            bf16x8 fa0 = *(const bf16x8*)(Asb + aO0 + (kb ^ aS0));
            bf16x8 fa1 = *(const bf16x8*)(Asb + aO1 + (kb ^ aS1));
            bf16x8 fb0 = *(const bf16x8*)(Bsb + bO0 + (kb ^ bS0));
            bf16x8 fb1 = *(const bf16x8*)(Bsb + bO1 + (kb ^ bS1));
            a00 = __builtin_amdgcn_mfma_f32_16x16x32_bf16(fa0, fb0, a00, 0, 0, 0);
            a01 = __builtin_amdgcn_mfma_f32_16x16x32_bf16(fa0, fb1, a01, 0, 0, 0);
            a10 = __builtin_amdgcn_mfma_f32_16x16x32_bf16(fa1, fb0, a10, 0, 0, 0);
            a11 = __builtin_amdgcn_mfma_f32_16x16x32_bf16(fa1, fb1, a11, 0, 0, 0);
        }
        {
            const int mBase = mt * 64 + wm * 32 + rb;
#pragma unroll
            for (int r = 0; r < 4; ++r) {
                int m = mBase + r;
                Cb[(size_t)m * FCH + cc]      = f2bf(a00[r]);
                Cb[(size_t)m * FCH + cc + 16] = f2bf(a01[r]);
                int m2 = m + 16;
                Cb[(size_t)m2 * FCH + cc]      = f2bf(a10[r]);
                Cb[(size_t)m2 * FCH + cc + 16] = f2bf(a11[r]);
            }
        }
        if (mtn >= NTILES) break;
        __syncthreads();
        writeA_lds(Asb, arow, akseg, buf);
        mt = mtn; mtn += mstep;
        __syncthreads();
        if (mtn < NTILES) loadA_raw(A, norm, mtn, arow, akseg, buf);
    }
}

// ============ agg layer 1: XCD-pinned feature chunk (chunk = blockIdx&7 -> XCD residency).
// H, out chunk-blocked [8][MPAD][32] bf16. 4 lanes/node x 16B; divergent per-node loop
// (masked lanes issue no traffic). 64 nodes/block.
__global__ __launch_bounds__(256) void agg1_kernel(const unsigned short* __restrict__ H,
                                                   const int* __restrict__ row_ptr,
                                                   const int* __restrict__ csr_src,
                                                   const float* __restrict__ norm_dst,
                                                   const float* __restrict__ norm_src,
                                                   const float* __restrict__ bias,
                                                   unsigned short* __restrict__ out) {
    const int c = blockIdx.x & 7;
    const int nb = blockIdx.x >> 3;
    const int tid = threadIdx.x;
    const int lane = tid & 63;
    const int g = lane >> 2;         // node slot in wave (0..15)
    const int f0 = (lane & 3) * 8;   // 8 bf16 = 16B
    const int node = nb * 64 + (tid >> 6) * 16 + g;   // < MPAD by grid

    const unsigned short* Hc = H + ((size_t)c * MPAD) * FCH + f0;
    float acc[8] = {};

    int e0 = 0, e1 = 0;
    if (node < NNODES) { e0 = row_ptr[node]; e1 = row_ptr[node + 1]; }

    for (int e = e0; e < e1; e += 4) {
        int i0 = csr_src[e];
        int i1 = csr_src[e + 1];
        int i2 = csr_src[e + 2];
        int i3 = csr_src[e + 3];
        i1 = (e + 1 < e1) ? i1 : NNODES;   // pad row = zeros
        i2 = (e + 2 < e1) ? i2 : NNODES;
        i3 = (e + 3 < e1) ? i3 : NNODES;
        uint4 v0 = *(const uint4*)(Hc + (size_t)i0 * FCH);
        uint4 v1 = *(const uint4*)(Hc + (size_t)i1 * FCH);
        uint4 v2 = *(const uint4*)(Hc + (size_t)i2 * FCH);
        uint4 v3 = *(const uint4*)(Hc + (size_t)i3 * FCH);
        const unsigned short* p0 = (const unsigned short*)&v0;
        const unsigned short* p1 = (const unsigned short*)&v1;
        const unsigned short* p2 = (const unsigned short*)&v2;
        const unsigned short* p3 = (const unsigned short*)&v3;
#pragma unroll
        for (int j = 0; j < 8; ++j)
            acc[j] += bf2f(p0[j]) + bf2f(p1[j]) + bf2f(p2[j]) + bf2f(p3[j]);
    }

    float nd = 0.f, ns = 0.f;
    if (node < NNODES) { nd = norm_dst[node]; ns = norm_src[node]; }
    const int fg = c * FCH + f0;
    union { uint4 u; unsigned short s[8]; } o;
#pragma unroll
    for (int j = 0; j < 8; ++j)
        o.s[j] = f2bf(fmaxf(fmaf(acc[j], nd, bias[fg + j]), 0.f) * ns);
    *(uint4*)(out + ((size_t)c * MPAD + node) * FCH + f0) = o.u;  // pads -> zeros (ns=0)
}

// ============ agg layer 2: 4 chunks of 32 feats, 2 XCDs per chunk (chunk=(bid&7)>>1).
// H chunk-blocked [4][MPAD][32] bf16; out row-major fp32 (final). No relu.
__global__ __launch_bounds__(256) void agg2_kernel(const unsigned short* __restrict__ H,
                                                   const int* __restrict__ row_ptr,
                                                   const int* __restrict__ csr_src,
                                                   const float* __restrict__ norm_dst,
                                                   const float* __restrict__ bias,
                                                   float* __restrict__ out) {
    const int c = (blockIdx.x & 7) >> 1;
    const int nb = (blockIdx.x >> 3) * 2 + (blockIdx.x & 1);
    const int tid = threadIdx.x;
    const int lane = tid & 63;
    const int g = lane >> 2;
    const int f0 = (lane & 3) * 8;
    const int node = nb * 64 + (tid >> 6) * 16 + g;
    if (node >= NNODES) return;

    const unsigned short* Hc = H + ((size_t)c * MPAD) * FCH + f0;
    float acc[8] = {};

    int e0 = row_ptr[node];
    int e1 = row_ptr[node + 1];

    for (int e = e0; e < e1; e += 4) {
        int i0 = csr_src[e];
        int i1 = csr_src[e + 1];
        int i2 = csr_src[e + 2];
        int i3 = csr_src[e + 3];
        i1 = (e + 1 < e1) ? i1 : NNODES;
        i2 = (e + 2 < e1) ? i2 : NNODES;
        i3 = (e + 3 < e1) ? i3 : NNODES;
        uint4 v0 = *(const uint4*)(Hc + (size_t)i0 * FCH);
        uint4 v1 = *(const uint4*)(Hc + (size_t)i1 * FCH);
        uint4 v2 = *(const uint4*)(Hc + (size_t)i2 * FCH);
        uint4 v3 = *(const uint4*)(Hc + (size_t)i3 * FCH);
        const unsigned short* p0 = (const unsigned short*)&v0;
        const unsigned short* p1 = (const unsigned short*)&v1;
        const unsigned short* p2 = (const unsigned short*)&v2;
        const unsigned short* p3 = (const unsigned short*)&v3;
#pragma unroll
        for (int j = 0; j < 8; ++j)
            acc[j] += bf2f(p0[j]) + bf2f(p1[j]) + bf2f(p2[j]) + bf2f(p3[j]);
    }

    float nd = norm_dst[node];
    const int fg = c * FCH + f0;
    float4 o1, o2;
    o1.x = fmaf(acc[0], nd, bias[fg + 0]);
    o1.y = fmaf(acc[1], nd, bias[fg + 1]);
    o1.z = fmaf(acc[2], nd, bias[fg + 2]);
    o1.w = fmaf(acc[3], nd, bias[fg + 3]);
    o2.x = fmaf(acc[4], nd, bias[fg + 4]);
    o2.y = fmaf(acc[5], nd, bias[fg + 5]);
    o2.z = fmaf(acc[6], nd, bias[fg + 6]);
    o2.w = fmaf(acc[7], nd, bias[fg + 7]);
    *(float4*)(out + (size_t)node * FOUT + fg) = o1;
    *(float4*)(out + (size_t)node * FOUT + fg + 4) = o2;
}

// ---------------- launch ----------------
extern "C" void kernel_launch(void* const* d_in, const int* in_sizes, int n_in,
                              void* d_out, int out_size, void* d_ws, size_t ws_size,
                              hipStream_t stream) {
    const float* x   = (const float*)d_in[0];
    const int*   src = (const int*)d_in[1];
    const int*   dst = (const int*)d_in[2];
    const float* W1  = (const float*)d_in[3];
    const float* b1  = (const float*)d_in[4];
    const float* W2  = (const float*)d_in[5];
    const float* b2  = (const float*)d_in[6];
    float* out = (float*)d_out;

    char* ws = (char*)d_ws;
    size_t off = 0;
    auto alloc = [&](size_t bytes) {
        char* p = ws + off;
        off += (bytes + 255) & ~(size_t)255;
        return p;
    };
    float* norm_src  = (float*)alloc(NNODES * 4);
    float* norm_dst  = (float*)alloc(NNODES * 4);
    int*   exD_arr   = (int*)alloc((size_t)256 * NB1 * 4);
    int*   exS_arr   = (int*)alloc((size_t)256 * NB1 * 4);
    unsigned int*  tmp1 = (unsigned int*)alloc((size_t)NEDGES * 4);
    unsigned char* tmp2 = (unsigned char*)alloc((size_t)NEDGES);
    int*   row_ptr   = (int*)alloc((NNODES + 16) * 4);
    int*   csr_src   = (int*)alloc((size_t)(NEDGES + 256) * 4);
    unsigned short* h   = (unsigned short*)alloc((size_t)MPAD * FH * 2);
    unsigned short* h1  = (unsigned short*)alloc((size_t)MPAD * FH * 2);
    unsigned short* Wt1 = (unsigned short*)alloc((size_t)FH * KDIM * 2);
    unsigned short* Wt2 = (unsigned short*)alloc((size_t)FOUT * KDIM * 2);
    unsigned short* h2  = h;

    l1_sort_cast<<<NB1 + 96, 256, 0, stream>>>(src, dst, tmp1, tmp2, exD_arr, exS_arr,
                                               W1, Wt1, W2, Wt2);
    l2_both<<<2 * NBUCK, 256, 0, stream>>>(tmp1, tmp2, exD_arr, exS_arr,
                                           row_ptr, norm_dst, norm_src, csr_src);

    // layer 1: h = bf16((x*norm_src) @ W1), chunk-blocked — B-resident, XCD-paired panels
    gemm_bres<float, true, 2><<<512, 512, 0, stream>>>(x, Wt1, norm_src, h);
    agg1_kernel<<<(MPAD / 64) * 8, 256, 0, stream>>>(h, row_ptr, csr_src, norm_dst, norm_src, b1, h1);

    // layer 2 — B-resident, single panel, chunk-blocked h2
    gemm_bres<unsigned short, false, 1><<<256, 512, 0, stream>>>(h1, Wt2, nullptr, h2);
    agg2_kernel<<<((MPAD / 64 + 1) / 2) * 8, 256, 0, stream>>>(h2, row_ptr, csr_src, norm_dst, b2, out);
}

// Round 7
// 239.095 us; speedup vs baseline: 1.0625x; 1.0625x over previous
//
#include <hip/hip_runtime.h>

#define NNODES 50000
#define MPAD   50048    // padded to multiple of 64 for MFMA tiles; rows 50000.. are zero pads
#define NEDGES 800000
#define KDIM   256      // in/hidden feature dim (GEMM K)
#define FH     256      // hidden feats
#define FOUT   128      // out feats
#define FCH    32       // feature chunk (bf16): 64B contiguous per node in blocked layout

// ---- counting-sort geometry ----
#define SHIFT  8
#define NBUCK  196              // ceil(50000/256); max dst>>8 = 195
#define NB1    200              // level-1 blocks
#define EPB    4000             // edges per level-1 block (NB1*EPB == NEDGES)

typedef __bf16 bf16x8 __attribute__((ext_vector_type(8)));
typedef float floatx4 __attribute__((ext_vector_type(4)));
typedef float floatx2 __attribute__((ext_vector_type(2)));

// 16B of indices at 4B alignment (csr segments are not 16B aligned)
struct int4u { int x, y, z, w; };

// ---------------- bf16 helpers (RNE) ----------------
__device__ __forceinline__ float bf2f(unsigned short u) {
    union { unsigned int i; float f; } v;
    v.i = ((unsigned int)u) << 16;
    return v.f;
}
__device__ __forceinline__ unsigned short f2bf(float f) {
    union { float f; unsigned int i; } v;
    v.f = f;
    unsigned int r = v.i + 0x7FFFu + ((v.i >> 16) & 1u);
    return (unsigned short)(r >> 16);
}

// packed bf16-pair accumulate: acc[k] += {lo(d), hi(d)} via v_pk_add_f32
__device__ __forceinline__ void acc_pairs(floatx2* acc, uint4 v) {
    unsigned int d[4] = {v.x, v.y, v.z, v.w};
#pragma unroll
    for (int k = 0; k < 4; ++k) {
        union { unsigned int u; float f; } lo, hi;
        lo.u = d[k] << 16;
        hi.u = d[k] & 0xFFFF0000u;
        floatx2 p = {lo.f, hi.f};
        acc[k] += p;
    }
}

// ============ P1: per-block counting sort, block-major output (no global scan needed)
__global__ __launch_bounds__(256) void l1_sort_cast(const int* __restrict__ src,
                                                    const int* __restrict__ dst,
                                                    unsigned int* __restrict__ tmp1,
                                                    unsigned char* __restrict__ tmp2,
                                                    int* __restrict__ exD_arr,
                                                    int* __restrict__ exS_arr,
                                                    const float* __restrict__ W1,
                                                    unsigned short* __restrict__ Wt1,
                                                    const float* __restrict__ W2,
                                                    unsigned short* __restrict__ Wt2) {
    __shared__ int histD[256], histS[256], exD[256], exS[256];
    __shared__ unsigned int bufD[EPB];
    __shared__ unsigned short bufS[EPB];
    __shared__ float tile[32][33];
    const int tid = threadIdx.x;

    if (blockIdx.x >= NB1) {
        int b = blockIdx.x - NB1;
        const float* W; unsigned short* Wt; int N;
        if (b < 64) { W = W1; Wt = Wt1; N = FH; }
        else        { b -= 64; W = W2; Wt = Wt2; N = FOUT; }
        int kt = (b & 7) * 32;
        int nt = (b >> 3) * 32;
        int tx = tid & 31;
        int ty = tid >> 5;
        for (int r = ty; r < 32; r += 8)
            tile[r][tx] = W[(size_t)(kt + r) * N + nt + tx];
        __syncthreads();
        for (int r = ty; r < 32; r += 8)
            Wt[(size_t)(nt + r) * KDIM + kt + tx] = f2bf(tile[tx][r]);
        return;
    }

    const int b = blockIdx.x;
    const int base = b * EPB;
    histD[tid] = 0; histS[tid] = 0;
    __syncthreads();
    for (int g = tid; g < EPB / 4; g += 256) {
        uint4 s4 = *(const uint4*)(src + base + g * 4);
        uint4 d4 = *(const uint4*)(dst + base + g * 4);
        atomicAdd(&histD[d4.x >> SHIFT], 1);
        atomicAdd(&histD[d4.y >> SHIFT], 1);
        atomicAdd(&histD[d4.z >> SHIFT], 1);
        atomicAdd(&histD[d4.w >> SHIFT], 1);
        atomicAdd(&histS[s4.x >> SHIFT], 1);
        atomicAdd(&histS[s4.y >> SHIFT], 1);
        atomicAdd(&histS[s4.z >> SHIFT], 1);
        atomicAdd(&histS[s4.w >> SHIFT], 1);
    }
    __syncthreads();
    int vD = histD[tid], vS = histS[tid];
    exD[tid] = vD; exS[tid] = vS;
    __syncthreads();
    for (int off = 1; off < 256; off <<= 1) {
        int tD = (tid >= off) ? exD[tid - off] : 0;
        int tS = (tid >= off) ? exS[tid - off] : 0;
        __syncthreads();
        exD[tid] += tD; exS[tid] += tS;
        __syncthreads();
    }
    int eD = exD[tid] - vD, eS = exS[tid] - vS;
    exD_arr[tid * NB1 + b] = eD;
    exS_arr[tid * NB1 + b] = eS;
    __syncthreads();
    histD[tid] = eD; histS[tid] = eS;
    __syncthreads();
    for (int g = tid; g < EPB / 4; g += 256) {
        uint4 s4 = *(const uint4*)(src + base + g * 4);
        uint4 d4 = *(const uint4*)(dst + base + g * 4);
        unsigned int ss[4] = {s4.x, s4.y, s4.z, s4.w};
        unsigned int dd[4] = {d4.x, d4.y, d4.z, d4.w};
#pragma unroll
        for (int j = 0; j < 4; ++j) {
            int p = atomicAdd(&histD[dd[j] >> SHIFT], 1);
            bufD[p] = (ss[j] << 16) | dd[j];
            int q = atomicAdd(&histS[ss[j] >> SHIFT], 1);
            bufS[q] = (unsigned short)ss[j];
        }
    }
    __syncthreads();
    for (int e = tid; e < EPB; e += 256) tmp1[base + e] = bufD[e];
    for (int e = tid; e < EPB; e += 256) tmp2[base + e] = (unsigned char)(bufS[e] & 255u);
}

// ============ P2: per-bucket finalize (dst: row_ptr/norm_dst/csr; src: norm_src) ==========
__global__ __launch_bounds__(256) void l2_both(const unsigned int* __restrict__ tmp1,
                                               const unsigned char* __restrict__ tmp2,
                                               const int* __restrict__ exD_arr,
                                               const int* __restrict__ exS_arr,
                                               int* __restrict__ row_ptr,
                                               float* __restrict__ norm_dst,
                                               float* __restrict__ norm_src,
                                               int* __restrict__ csr_src) {
    __shared__ int cnt[256], ofs[256], cur[256], red[256];
    __shared__ int segoff[NB1], seglen[NB1];
    const int tid = threadIdx.x;

    if (blockIdx.x >= NBUCK) {
        const int k = blockIdx.x - NBUCK;
        if (tid < NB1) {
            int e0 = exS_arr[k * NB1 + tid];
            segoff[tid] = tid * EPB + e0;
            seglen[tid] = exS_arr[(k + 1) * NB1 + tid] - e0;
        }
        cnt[tid] = 0;
        __syncthreads();
        if (tid < NB1) {
            int so = segoff[tid], sl = seglen[tid];
            for (int i = 0; i < sl; ++i)
                atomicAdd(&cnt[tmp2[so + i]], 1);
        }
        __syncthreads();
        int node = k * 256 + tid;
        if (node < NNODES) {
            int d = cnt[tid] < 1 ? 1 : cnt[tid];
            norm_src[node] = 1.0f / sqrtf((float)d);
        }
        return;
    }

    const int k = blockIdx.x;
    int e0v = 0;
    if (tid < NB1) {
        e0v = exD_arr[k * NB1 + tid];
        segoff[tid] = tid * EPB + e0v;
        seglen[tid] = exD_arr[(k + 1) * NB1 + tid] - e0v;
    }
    red[tid] = (tid < NB1) ? e0v : 0;
    cnt[tid] = 0;
    __syncthreads();
    for (int off = 128; off > 0; off >>= 1) {
        if (tid < off) red[tid] += red[tid + off];
        __syncthreads();
    }
    const int base = red[0];
    if (tid < NB1) {
        int so = segoff[tid], sl = seglen[tid];
        for (int i = 0; i < sl; ++i)
            atomicAdd(&cnt[tmp1[so + i] & 255u], 1);
    }
    __syncthreads();
    int v = cnt[tid];
    ofs[tid] = v;
    __syncthreads();
    for (int off = 1; off < 256; off <<= 1) {
        int t = (tid >= off) ? ofs[tid - off] : 0;
        __syncthreads();
        ofs[tid] += t;
        __syncthreads();
    }
    int excl = ofs[tid] - v;
    int node = k * 256 + tid;
    if (node < NNODES) {
        row_ptr[node] = base + excl;
        int d = v < 1 ? 1 : v;
        norm_dst[node] = 1.0f / sqrtf((float)d);
    }
    cur[tid] = base + excl;
    if (k == 0 && tid == 0) row_ptr[NNODES] = NEDGES;
    __syncthreads();
    if (tid < NB1) {
        int so = segoff[tid], sl = seglen[tid];
        for (int i = 0; i < sl; ++i) {
            unsigned int p = tmp1[so + i];
            int pos = atomicAdd(&cur[p & 255u], 1);
            csr_src[pos] = (int)(p >> 16);
        }
    }
}

// ================= B-resident GEMM; C written CHUNK-BLOCKED [(n/32)][MPAD][32] =============
struct arawF { float4 v[8]; float sc; };
struct arawU { uint4 v[4]; };
template <typename TA> struct rawsel;
template <> struct rawsel<float> { using type = arawF; };
template <> struct rawsel<unsigned short> { using type = arawU; };

__device__ __forceinline__ void loadA_raw(const float* A, const float* norm,
                                          int mt, int arow, int akseg, arawF& r) {
    int row = mt * 64 + arow;
    if (row < NNODES) {
        const float* p = A + (size_t)row * KDIM + akseg;
#pragma unroll
        for (int j = 0; j < 8; ++j) r.v[j] = *(const float4*)(p + j * 4);
        r.sc = norm[row];
    } else {
        float4 z = {0.f, 0.f, 0.f, 0.f};
#pragma unroll
        for (int j = 0; j < 8; ++j) r.v[j] = z;
        r.sc = 0.f;
    }
}
// h1 is chunk-blocked: feats akseg..akseg+31 of row = contiguous 64B at ((akseg/32)*MPAD+row)*32
__device__ __forceinline__ void loadA_raw(const unsigned short* A, const float*,
                                          int mt, int arow, int akseg, arawU& r) {
    const unsigned short* p = A + ((size_t)(akseg >> 5) * MPAD + mt * 64 + arow) * FCH;
#pragma unroll
    for (int j = 0; j < 4; ++j) r.v[j] = *(const uint4*)(p + j * 8);
}
__device__ __forceinline__ void writeA_lds(char* Asb, int arow, int akseg, const arawF& r) {
    const int s = (arow & 7) << 4;
    const int base = arow * 512;
#pragma unroll
    for (int j = 0; j < 4; ++j) {
        union { uint4 u; unsigned short h[8]; } o;
        float4 a = r.v[2 * j], b = r.v[2 * j + 1];
        o.h[0] = f2bf(a.x * r.sc); o.h[1] = f2bf(a.y * r.sc);
        o.h[2] = f2bf(a.z * r.sc); o.h[3] = f2bf(a.w * r.sc);
        o.h[4] = f2bf(b.x * r.sc); o.h[5] = f2bf(b.y * r.sc);
        o.h[6] = f2bf(b.z * r.sc); o.h[7] = f2bf(b.w * r.sc);
        *(uint4*)(Asb + base + (((akseg + j * 8) * 2) ^ s)) = o.u;
    }
}
__device__ __forceinline__ void writeA_lds(char* Asb, int arow, int akseg, const arawU& r) {
    const int s = (arow & 7) << 4;
    const int base = arow * 512;
#pragma unroll
    for (int j = 0; j < 4; ++j)
        *(uint4*)(Asb + base + (((akseg + j * 8) * 2) ^ s)) = r.v[j];
}

template <typename TA, bool SCALE, int NPANEL>
__global__ __launch_bounds__(512) void gemm_bres(const TA* __restrict__ A,
                                                 const unsigned short* __restrict__ Bt,
                                                 const float* __restrict__ norm,
                                                 unsigned short* __restrict__ C) {
    constexpr int NTILES = MPAD / 64;
    __shared__ __align__(16) unsigned short Bs[128 * 256];   // 64KB, [col][k] swizzled
    __shared__ __align__(16) unsigned short As[64 * 256];    // 32KB, [row][k] swizzled
    char* Bsb = (char*)Bs;
    char* Asb = (char*)As;

    const int tid = threadIdx.x;
    const int lane = tid & 63;
    const int wave = tid >> 6;

    int col0, mt0, mstep;
    if (NPANEL == 2) {
        col0 = ((blockIdx.x >> 3) & 1) * 128;
        mt0 = ((blockIdx.x >> 4) << 3) + (blockIdx.x & 7);
        mstep = gridDim.x >> 1;
    } else {
        col0 = 0;
        mt0 = blockIdx.x;
        mstep = gridDim.x;
    }

    {
        int col = tid >> 2;
        int kq = (tid & 3) * 64;
        const unsigned short* bg = Bt + (size_t)(col0 + col) * KDIM + kq;
        const int s = (col & 7) << 4;
        const int base = col * 512;
#pragma unroll
        for (int j = 0; j < 8; ++j) {
            uint4 v = *(const uint4*)(bg + j * 8);
            *(uint4*)(Bsb + base + (((kq + j * 8) * 2) ^ s)) = v;
        }
    }

    const int arow = tid >> 3;
    const int akseg = (tid & 7) * 32;

    typename rawsel<TA>::type buf;
    loadA_raw(A, norm, mt0, arow, akseg, buf);
    writeA_lds(Asb, arow, akseg, buf);
    __syncthreads();
    int mt = mt0, mtn = mt0 + mstep;
    if (mtn < NTILES) loadA_raw(A, norm, mtn, arow, akseg, buf);

    const int wn = wave & 3, wm = wave >> 2;
    const int ar = lane & 15;
    const int fkb = (lane >> 4) << 4;
    const int rA0 = wm * 32 + ar,  rA1 = rA0 + 16;
    const int cB0 = wn * 32 + ar,  cB1 = cB0 + 16;
    const int aO0 = rA0 * 512, aS0 = (rA0 & 7) << 4;
    const int aO1 = rA1 * 512, aS1 = (rA1 & 7) << 4;
    const int bO0 = cB0 * 512, bS0 = (cB0 & 7) << 4;
    const int bO1 = cB1 * 512, bS1 = (cB1 & 7) << 4;
    const int rb = (lane >> 4) << 2, cc = lane & 15;

    // chunk is wave-uniform: cols col0+wn*32 .. +31 == chunk (col0>>5)+wn
    unsigned short* Cb = C + ((size_t)((col0 >> 5) + wn) * MPAD) * FCH;

    for (;;) {
        floatx4 a00 = {}, a01 = {}, a10 = {}, a11 = {};
#pragma unroll
        for (int kk = 0; kk < 8; ++kk) {
            const int kb = kk * 64 + fkb;
            bf16x8 fa0 = *(const bf16x8*)(Asb + aO0 + (kb ^ aS0));
            bf16x8 fa1 = *(const bf16x8*)(Asb + aO1 + (kb ^ aS1));
            bf16x8 fb0 = *(const bf16x8*)(Bsb + bO0 + (kb ^ bS0));
            bf16x8 fb1 = *(const bf16x8*)(Bsb + bO1 + (kb ^ bS1));
            a00 = __builtin_amdgcn_mfma_f32_16x16x32_bf16(fa0, fb0, a00, 0, 0, 0);
            a01 = __builtin_amdgcn_mfma_f32_16x16x32_bf16(fa0, fb1, a01, 0, 0, 0);
            a10 = __builtin_amdgcn_mfma_f32_16x16x32_bf16(fa1, fb0, a10, 0, 0, 0);
            a11 = __builtin_amdgcn_mfma_f32_16x16x32_bf16(fa1, fb1, a11, 0, 0, 0);
        }
        {
            const int mBase = mt * 64 + wm * 32 + rb;
#pragma unroll
            for (int r = 0; r < 4; ++r) {
                int m = mBase + r;
                Cb[(size_t)m * FCH + cc]      = f2bf(a00[r]);
                Cb[(size_t)m * FCH + cc + 16] = f2bf(a01[r]);
                int m2 = m + 16;
                Cb[(size_t)m2 * FCH + cc]      = f2bf(a10[r]);
                Cb[(size_t)m2 * FCH + cc + 16] = f2bf(a11[r]);
            }
        }
        if (mtn >= NTILES) break;
        __syncthreads();
        writeA_lds(Asb, arow, akseg, buf);
        mt = mtn; mtn += mstep;
        __syncthreads();
        if (mtn < NTILES) loadA_raw(A, norm, mtn, arow, akseg, buf);
    }
}

// ============ agg layer 1: XCD-pinned feature chunk (chunk = blockIdx&7), chunk-blocked
// [8][MPAD][32]. 4 lanes/node x 16B gathers; 8-edge software pipeline (index prefetch),
// packed float2 accumulate (v_pk_add_f32). Pad rows write zeros (ns=0).
__global__ __launch_bounds__(256) void agg1_kernel(const unsigned short* __restrict__ H,
                                                   const int* __restrict__ row_ptr,
                                                   const int* __restrict__ csr_src,
                                                   const float* __restrict__ norm_dst,
                                                   const float* __restrict__ norm_src,
                                                   const float* __restrict__ bias,
                                                   unsigned short* __restrict__ out) {
    const int c = blockIdx.x & 7;
    const int nb = blockIdx.x >> 3;
    const int tid = threadIdx.x;
    const int lane = tid & 63;
    const int g = lane >> 2;         // node slot (0..15)
    const int f0 = (lane & 3) * 8;   // 8 bf16 = 16B
    const int node = nb * 64 + (tid >> 6) * 16 + g;   // < MPAD by grid

    const unsigned short* Hc = H + ((size_t)c * MPAD) * FCH + f0;
    floatx2 acc[4] = {};

    int e0 = 0, e1 = 0;
    if (node < NNODES) { e0 = row_ptr[node]; e1 = row_ptr[node + 1]; }

    if (e0 < e1) {
        int4u ia = *(const int4u*)(csr_src + e0);
        int4u ib = *(const int4u*)(csr_src + e0 + 4);
        for (int e = e0; e < e1; e += 8) {
            const int ecnt = e1 - e;
            int idx[8] = {ia.x, ia.y, ia.z, ia.w, ib.x, ib.y, ib.z, ib.w};
#pragma unroll
            for (int j = 1; j < 8; ++j) idx[j] = (j < ecnt) ? idx[j] : NNODES;
            if (e + 8 < e1) {           // prefetch next indices under the gathers
                ia = *(const int4u*)(csr_src + e + 8);
                ib = *(const int4u*)(csr_src + e + 12);
            }
            uint4 w[8];
#pragma unroll
            for (int j = 0; j < 8; ++j)
                w[j] = *(const uint4*)(Hc + (size_t)idx[j] * FCH);
#pragma unroll
            for (int j = 0; j < 8; ++j) acc_pairs(acc, w[j]);
        }
    }

    float nd = 0.f, ns = 0.f;
    if (node < NNODES) { nd = norm_dst[node]; ns = norm_src[node]; }
    const int fg = c * FCH + f0;
    float4 b0 = *(const float4*)(bias + fg);
    float4 b1v = *(const float4*)(bias + fg + 4);
    float bb[8] = {b0.x, b0.y, b0.z, b0.w, b1v.x, b1v.y, b1v.z, b1v.w};
    union { uint4 u; unsigned short s[8]; } o;
#pragma unroll
    for (int k = 0; k < 4; ++k) {
        o.s[2 * k]     = f2bf(fmaxf(fmaf(acc[k].x, nd, bb[2 * k]), 0.f) * ns);
        o.s[2 * k + 1] = f2bf(fmaxf(fmaf(acc[k].y, nd, bb[2 * k + 1]), 0.f) * ns);
    }
    *(uint4*)(out + ((size_t)c * MPAD + node) * FCH + f0) = o.u;
}

// ============ agg layer 2: 4 chunks, 2 XCDs/chunk. Same 8-edge pipeline + packed acc.
// H chunk-blocked [4][MPAD][32]; out row-major fp32, no relu.
__global__ __launch_bounds__(256) void agg2_kernel(const unsigned short* __restrict__ H,
                                                   const int* __restrict__ row_ptr,
                                                   const int* __restrict__ csr_src,
                                                   const float* __restrict__ norm_dst,
                                                   const float* __restrict__ bias,
                                                   float* __restrict__ out) {
    const int c = (blockIdx.x & 7) >> 1;
    const int nb = (blockIdx.x >> 3) * 2 + (blockIdx.x & 1);
    const int tid = threadIdx.x;
    const int lane = tid & 63;
    const int g = lane >> 2;
    const int f0 = (lane & 3) * 8;
    const int node = nb * 64 + (tid >> 6) * 16 + g;
    if (node >= NNODES) return;

    const unsigned short* Hc = H + ((size_t)c * MPAD) * FCH + f0;
    floatx2 acc[4] = {};

    int e0 = row_ptr[node];
    int e1 = row_ptr[node + 1];

    if (e0 < e1) {
        int4u ia = *(const int4u*)(csr_src + e0);
        int4u ib = *(const int4u*)(csr_src + e0 + 4);
        for (int e = e0; e < e1; e += 8) {
            const int ecnt = e1 - e;
            int idx[8] = {ia.x, ia.y, ia.z, ia.w, ib.x, ib.y, ib.z, ib.w};
#pragma unroll
            for (int j = 1; j < 8; ++j) idx[j] = (j < ecnt) ? idx[j] : NNODES;
            if (e + 8 < e1) {
                ia = *(const int4u*)(csr_src + e + 8);
                ib = *(const int4u*)(csr_src + e + 12);
            }
            uint4 w[8];
#pragma unroll
            for (int j = 0; j < 8; ++j)
                w[j] = *(const uint4*)(Hc + (size_t)idx[j] * FCH);
#pragma unroll
            for (int j = 0; j < 8; ++j) acc_pairs(acc, w[j]);
        }
    }

    float nd = norm_dst[node];
    const int fg = c * FCH + f0;
    float4 b0 = *(const float4*)(bias + fg);
    float4 b1v = *(const float4*)(bias + fg + 4);
    float4 o1, o2;
    o1.x = fmaf(acc[0].x, nd, b0.x);
    o1.y = fmaf(acc[0].y, nd, b0.y);
    o1.z = fmaf(acc[1].x, nd, b0.z);
    o1.w = fmaf(acc[1].y, nd, b0.w);
    o2.x = fmaf(acc[2].x, nd, b1v.x);
    o2.y = fmaf(acc[2].y, nd, b1v.y);
    o2.z = fmaf(acc[3].x, nd, b1v.z);
    o2.w = fmaf(acc[3].y, nd, b1v.w);
    *(float4*)(out + (size_t)node * FOUT + fg) = o1;
    *(float4*)(out + (size_t)node * FOUT + fg + 4) = o2;
}

// ---------------- launch ----------------
extern "C" void kernel_launch(void* const* d_in, const int* in_sizes, int n_in,
                              void* d_out, int out_size, void* d_ws, size_t ws_size,
                              hipStream_t stream) {
    const float* x   = (const float*)d_in[0];
    const int*   src = (const int*)d_in[1];
    const int*   dst = (const int*)d_in[2];
    const float* W1  = (const float*)d_in[3];
    const float* b1  = (const float*)d_in[4];
    const float* W2  = (const float*)d_in[5];
    const float* b2  = (const float*)d_in[6];
    float* out = (float*)d_out;

    char* ws = (char*)d_ws;
    size_t off = 0;
    auto alloc = [&](size_t bytes) {
        char* p = ws + off;
        off += (bytes + 255) & ~(size_t)255;
        return p;
    };
    float* norm_src  = (float*)alloc(NNODES * 4);
    float* norm_dst  = (float*)alloc(NNODES * 4);
    int*   exD_arr   = (int*)alloc((size_t)256 * NB1 * 4);
    int*   exS_arr   = (int*)alloc((size_t)256 * NB1 * 4);
    unsigned int*  tmp1 = (unsigned int*)alloc((size_t)NEDGES * 4);
    unsigned char* tmp2 = (unsigned char*)alloc((size_t)NEDGES);
    int*   row_ptr   = (int*)alloc((NNODES + 16) * 4);
    int*   csr_src   = (int*)alloc((size_t)(NEDGES + 256) * 4);
    unsigned short* h   = (unsigned short*)alloc((size_t)MPAD * FH * 2);
    unsigned short* h1  = (unsigned short*)alloc((size_t)MPAD * FH * 2);
    unsigned short* Wt1 = (unsigned short*)alloc((size_t)FH * KDIM * 2);
    unsigned short* Wt2 = (unsigned short*)alloc((size_t)FOUT * KDIM * 2);
    unsigned short* h2  = h;

    l1_sort_cast<<<NB1 + 96, 256, 0, stream>>>(src, dst, tmp1, tmp2, exD_arr, exS_arr,
                                               W1, Wt1, W2, Wt2);
    l2_both<<<2 * NBUCK, 256, 0, stream>>>(tmp1, tmp2, exD_arr, exS_arr,
                                           row_ptr, norm_dst, norm_src, csr_src);

    // layer 1: h = bf16((x*norm_src) @ W1), chunk-blocked — B-resident, XCD-paired panels
    gemm_bres<float, true, 2><<<512, 512, 0, stream>>>(x, Wt1, norm_src, h);
    agg1_kernel<<<(MPAD / 64) * 8, 256, 0, stream>>>(h, row_ptr, csr_src, norm_dst, norm_src, b1, h1);

    // layer 2 — B-resident, single panel, chunk-blocked h2
    gemm_bres<unsigned short, false, 1><<<256, 512, 0, stream>>>(h1, Wt2, nullptr, h2);
    agg2_kernel<<<((MPAD / 64 + 1) / 2) * 8, 256, 0, stream>>>(h2, row_ptr, csr_src, norm_dst, b2, out);
}